// Round 20
// baseline (50.853 us; speedup 1.0000x reference)
//
#include <hip/hip_runtime.h>
#include <math.h>

#define NROWS 4096
#define DIM   512
#define BM    128
#define BKB   128               // K-tile in elements(=bytes, int8)
#define NKT   (DIM / BKB)       // 4
#define NTILE (NROWS / BM)      // 32
#define NBLK  (NTILE * (NTILE + 1) / 2)  // 528 (= 8 x 66)

typedef __attribute__((ext_vector_type(4))) float f32x4;
typedef __attribute__((ext_vector_type(4))) int   i32x4;

// ws layout (bytes):
// [0, 32)            ctrl: double loss | uint pair_cnt | uint done | pad
// [64,    16448)     float magf[4096]   (real-unit squared norms)
// [16448, 32832)     float srow[4096]   (per-row dequant scale)
// [32832, 557120)    float part[4096][32]  (f32 negsum partials, row-major)
// [557120, 2654272)  int8 Xq[4096*512]  (2 MB)
// [2654272, ...)     pairs: uint2 {(i<<16)|j, float_bits(dist)}
#define CTRL_OFF 0
#define MAGF_OFF 64
#define SROW_OFF (MAGF_OFF + NROWS * 4)            // 16448
#define PART_OFF (SROW_OFF + NROWS * 4)            // 32832
#define XQ_OFF   (PART_OFF + NROWS * NTILE * 4)    // 557120
#define PAIR_OFF (XQ_OFF + NROWS * DIM)            // 2654272

// quantize with PER-ROW scale (exact: d2 = |s_i q_i - s_j q_j|^2) + ctrl zero.
// One wave per row; row (2 KB) held in registers, single pass over X.
__global__ void quant_kernel(const float* __restrict__ X,
                             signed char* __restrict__ Xq,
                             float* __restrict__ magf,
                             float* __restrict__ srow,
                             unsigned int* __restrict__ ctrl) {
    if (blockIdx.x == 0 && threadIdx.x < 4) ctrl[threadIdx.x] = 0u;
    int row  = blockIdx.x * 4 + (threadIdx.x >> 6);
    int lane = threadIdx.x & 63;
    const float4* p = reinterpret_cast<const float4*>(X + (size_t)row * DIM);
    float4 v0 = p[lane], v1 = p[lane + 64];
    float m = fmaxf(fmaxf(fmaxf(fabsf(v0.x), fabsf(v0.y)),
                          fmaxf(fabsf(v0.z), fabsf(v0.w))),
                    fmaxf(fmaxf(fabsf(v1.x), fabsf(v1.y)),
                          fmaxf(fabsf(v1.z), fabsf(v1.w))));
#pragma unroll
    for (int o = 1; o < 64; o <<= 1) m = fmaxf(m, __shfl_xor(m, o));
    float s = m > 1e-20f ? 126.0f / m : 1.0f;

    int c[8];
    c[0] = (int)rintf(v0.x * s); c[1] = (int)rintf(v0.y * s);
    c[2] = (int)rintf(v0.z * s); c[3] = (int)rintf(v0.w * s);
    c[4] = (int)rintf(v1.x * s); c[5] = (int)rintf(v1.y * s);
    c[6] = (int)rintf(v1.z * s); c[7] = (int)rintf(v1.w * s);
    int acc = 0;
#pragma unroll
    for (int k = 0; k < 8; k++) {
        c[k] = max(-127, min(127, c[k]));
        acc += c[k] * c[k];
    }
    unsigned int* o = reinterpret_cast<unsigned int*>(Xq + (size_t)row * DIM);
    o[lane] = (unsigned int)(c[0] & 255) | ((unsigned int)(c[1] & 255) << 8) |
              ((unsigned int)(c[2] & 255) << 16) | ((unsigned int)(c[3] & 255) << 24);
    o[lane + 64] = (unsigned int)(c[4] & 255) | ((unsigned int)(c[5] & 255) << 8) |
                   ((unsigned int)(c[6] & 255) << 16) | ((unsigned int)(c[7] & 255) << 24);
#pragma unroll
    for (int off = 32; off; off >>= 1) acc += __shfl_down(acc, off);
    if (lane == 0) {
        float sr = 1.0f / s;                    // dequant scale
        srow[row] = sr;
        magf[row] = (sr * sr) * (float)acc;     // real-unit |x_q|^2
    }
}

// int8 MFMA GEMM, exact quantized distances. Proven structure:
// 128x128 triangular tiles, rolled NKT=4 K-loop, 8x16B-chunk XOR swizzle.
__global__ __launch_bounds__(256, 3) void sim_mfma(
        const signed char* __restrict__ Xq, const int* __restrict__ tgt,
        const float* __restrict__ magf, const float* __restrict__ srow,
        float* __restrict__ part,
        unsigned int* __restrict__ pair_cnt, uint2* __restrict__ pairs,
        unsigned int cap) {
    __shared__ signed char As[BM * BKB];   // 16 KB
    __shared__ signed char Bs[BM * BKB];   // 16 KB

    const int tid  = threadIdx.x;
    const int lane = tid & 63;
    const int wid  = tid >> 6;        // 4 waves: 2x2 of 64x64
    const int wr   = wid >> 1, wc = wid & 1;
    const int l15  = lane & 15;
    const int lg   = lane >> 4;       // 0..3

    // XCD swizzle: 528 = 8 x 66, contiguous runs per XCD
    int b = blockIdx.x;
    int t = (b & 7) * 66 + (b >> 3);
    int bi = (int)((65.0f - sqrtf(4225.0f - 8.0f * (float)t)) * 0.5f);
    if (bi < 0) bi = 0;
    if (bi > NTILE - 1) bi = NTILE - 1;
    while ((65 * (bi + 1) - (bi + 1) * (bi + 1)) / 2 <= t) bi++;
    while ((65 * bi - bi * bi) / 2 > t) bi--;
    int bj = bi + (t - (65 * bi - bi * bi) / 2);
    const int rowBase = bi * BM;
    const int colBase = bj * BM;
    const bool offd = (bi != bj);

    i32x4 acc[4][4];
#pragma unroll
    for (int m = 0; m < 4; m++)
#pragma unroll
        for (int n = 0; n < 4; n++) acc[m][n] = (i32x4){0, 0, 0, 0};

    // ROLLED K-loop. Row = 128 B = 8 x 16B chunks; LDS slot (r, ch) holds
    // global chunk ch^(r&7) (read-side XOR, linear LDS dest - rule #21).
#pragma unroll 1
    for (int kt = 0; kt < NKT; kt++) {
        const int k0 = kt * BKB;
        __syncthreads();
#pragma unroll
        for (int c = 0; c < 4; c++) {
            int chunkBase = (c * 4 + wid) * 64;      // wave-uniform
            int idx = chunkBase + lane;              // 0..1023
            int r   = idx >> 3;
            int ch  = idx & 7;
            int gch = ch ^ (r & 7);
            const signed char* ga = Xq + (size_t)(rowBase + r) * DIM + k0 + gch * 16;
            __builtin_amdgcn_global_load_lds(
                (const __attribute__((address_space(1))) void*)ga,
                (__attribute__((address_space(3))) void*)(As + chunkBase * 16),
                16, 0, 0);
            const signed char* gb = Xq + (size_t)(colBase + r) * DIM + k0 + gch * 16;
            __builtin_amdgcn_global_load_lds(
                (const __attribute__((address_space(1))) void*)gb,
                (__attribute__((address_space(3))) void*)(Bs + chunkBase * 16),
                16, 0, 0);
        }
        __syncthreads();

#pragma unroll
        for (int ksub = 0; ksub < 2; ksub++) {
            i32x4 af[4], bf[4];
#pragma unroll
            for (int m = 0; m < 4; m++) {
                int ra = wr * 64 + m * 16 + l15;
                int cs = (ksub * 4 + lg) ^ (ra & 7);
                af[m] = *reinterpret_cast<const i32x4*>(&As[ra * BKB + cs * 16]);
            }
#pragma unroll
            for (int n = 0; n < 4; n++) {
                int rb = wc * 64 + n * 16 + l15;
                int cs = (ksub * 4 + lg) ^ (rb & 7);
                bf[n] = *reinterpret_cast<const i32x4*>(&Bs[rb * BKB + cs * 16]);
            }
#pragma unroll
            for (int m = 0; m < 4; m++)
#pragma unroll
                for (int n = 0; n < 4; n++)
                    acc[m][n] = __builtin_amdgcn_mfma_i32_16x16x64_i8(
                        af[m], bf[n], acc[m][n], 0, 0, 0);
        }
    }

    // ---- fused epilogue ----
    // C/D layout: col = lane&15, row = (lane>>4)*4 + reg (dtype-independent)
    int gcol[4], tgj[4];
    float mj[4], sj[4];
#pragma unroll
    for (int n = 0; n < 4; n++) {
        gcol[n] = colBase + wc * 64 + n * 16 + l15;
        tgj[n]  = tgt[gcol[n]];
        mj[n]   = magf[gcol[n]];
        sj[n]   = srow[gcol[n]];
    }
    int grow[4][4], tgi[4][4];
    float mi[4][4], si[4][4];
#pragma unroll
    for (int m = 0; m < 4; m++)
#pragma unroll
        for (int q = 0; q < 4; q++) {
            grow[m][q] = rowBase + wr * 64 + m * 16 + lg * 4 + q;
            tgi[m][q]  = tgt[grow[m][q]];
            mi[m][q]   = magf[grow[m][q]];
            si[m][q]   = srow[grow[m][q]];
        }

    float negrow[4][4];
    float negcol[4] = {0.f, 0.f, 0.f, 0.f};
#pragma unroll
    for (int m = 0; m < 4; m++)
#pragma unroll
        for (int q = 0; q < 4; q++) negrow[m][q] = 0.f;

    // pass A: real-unit d2 -> dist (overwrites acc with dist bits)
    int mycnt = 0;
#pragma unroll
    for (int m = 0; m < 4; m++)
#pragma unroll
        for (int n = 0; n < 4; n++)
#pragma unroll
            for (int q = 0; q < 4; q++) {
                float ss   = si[m][q] * sj[n];
                float d2   = (mi[m][q] + mj[n]) - 2.0f * (ss * (float)acc[m][n][q]);
                float dist = d2 > 0.f ? sqrtf(d2) : 0.f;
                acc[m][n][q] = __float_as_int(dist);
                if (tgi[m][q] != tgj[n]) {
                    if (dist != 0.f) {
                        float e = __expf(1.0f - dist);
                        negrow[m][q] += e;
                        if (offd) negcol[n] += e;
                    }
                } else if (grow[m][q] < gcol[n]) {
                    mycnt++;
                }
            }

    __syncthreads();   // K-loop LDS dead; overlay epilogue buffers
    float* rowbuf = (float*)&As[0];            // [2][128] floats
    float* colbuf = (float*)&As[2048];         // [2][128] floats
    unsigned int* scan = (unsigned int*)&Bs[0];

#pragma unroll
    for (int m = 0; m < 4; m++)
#pragma unroll
        for (int q = 0; q < 4; q++) {
            float v = negrow[m][q];
            v += __shfl_xor(v, 1); v += __shfl_xor(v, 2);
            v += __shfl_xor(v, 4); v += __shfl_xor(v, 8);
            if (l15 == 0) rowbuf[wc * 128 + wr * 64 + m * 16 + lg * 4 + q] = v;
        }
#pragma unroll
    for (int n = 0; n < 4; n++) {
        float v = negcol[n];
        v += __shfl_xor(v, 16); v += __shfl_xor(v, 32);
        if (lg == 0) colbuf[wr * 128 + wc * 64 + n * 16 + l15] = v;
    }

    unsigned int pc = (unsigned int)mycnt;
    unsigned int incl = pc;
#pragma unroll
    for (int d = 1; d < 64; d <<= 1) {
        unsigned int tshf = __shfl_up(incl, d);
        if (lane >= d) incl += tshf;
    }
    if (lane == 63) scan[wid] = incl;
    __syncthreads();

    // collision-free f32 partial stores: part[row][tile], unique writer/slot
    if (tid < BM) {
        float rv = rowbuf[tid] + rowbuf[128 + tid];
        part[(size_t)(rowBase + tid) * NTILE + bj] = rv;
        if (offd) {
            float cv = colbuf[tid] + colbuf[128 + tid];
            part[(size_t)(colBase + tid) * NTILE + bi] = cv;
        }
    }

    unsigned int woff = 0;
#pragma unroll
    for (int w = 0; w < 4; w++)
        if (w < wid) woff += scan[w];
    unsigned int btot = scan[0] + scan[1] + scan[2] + scan[3];
    if (tid == 0) scan[4] = btot ? atomicAdd(pair_cnt, btot) : 0u;
    __syncthreads();
    unsigned int mybase = scan[4] + woff + (incl - pc);

    if (pc) {
        unsigned int idx = mybase;
#pragma unroll
        for (int m = 0; m < 4; m++)
#pragma unroll
            for (int n = 0; n < 4; n++)
#pragma unroll
                for (int q = 0; q < 4; q++) {
                    if (tgi[m][q] == tgj[n] && grow[m][q] < gcol[n]) {
                        if (idx < cap) {
                            uint2 e;
                            e.x = ((unsigned int)grow[m][q] << 16) | (unsigned int)gcol[n];
                            e.y = (unsigned int)acc[m][n][q];   // dist bits
                            pairs[idx] = e;
                        }
                        idx++;
                    }
                }
    }
}

// pair loss sum with INLINE row_neg gather (f32 partials, 2x8 float4 loads,
// L2-hot) + fused finalize. Replaces the separate reduce launch.
__global__ void pair_kernel(const uint2* __restrict__ pairs,
                            const unsigned int* __restrict__ pair_cnt,
                            const float* __restrict__ part,
                            unsigned int cap, double* __restrict__ loss,
                            unsigned int* __restrict__ done,
                            float* __restrict__ out) {
    __shared__ double red[256];
    unsigned int n = *pair_cnt;
    if (n > cap) n = cap;
    double local = 0.0;
    for (unsigned int p = blockIdx.x * blockDim.x + threadIdx.x; p < n;
         p += gridDim.x * blockDim.x) {
        uint2 e = pairs[p];
        int i = (int)(e.x >> 16), j = (int)(e.x & 0xffffu);
        float d = __int_as_float((int)e.y);
        const float4* pi = reinterpret_cast<const float4*>(part + (size_t)i * NTILE);
        const float4* pj = reinterpret_cast<const float4*>(part + (size_t)j * NTILE);
        float ni = 0.f, nj = 0.f;
#pragma unroll
        for (int k = 0; k < 8; k++) {
            float4 a = pi[k], bq = pj[k];
            ni += (a.x + a.y) + (a.z + a.w);
            nj += (bq.x + bq.y) + (bq.z + bq.w);
        }
        float J = logf(ni + nj) + d;
        if (J > 0.f) local += (double)J * (double)J;
    }
    red[threadIdx.x] = local;
    __syncthreads();
    for (int s = 128; s; s >>= 1) {
        if (threadIdx.x < (unsigned)s) red[threadIdx.x] += red[threadIdx.x + s];
        __syncthreads();
    }
    if (threadIdx.x == 0) {
        atomicAdd(loss, red[0]);
        __threadfence();
        unsigned int tk = atomicAdd(done, 1u);
        if (tk == gridDim.x - 1) {
            double l = atomicAdd(loss, 0.0);
            out[0] = (float)(l / (2.0 * (double)(*pair_cnt)));
        }
    }
}

extern "C" void kernel_launch(void* const* d_in, const int* in_sizes, int n_in,
                              void* d_out, int out_size, void* d_ws, size_t ws_size,
                              hipStream_t stream) {
    const float* X = (const float*)d_in[0];
    const int* tgt = (const int*)d_in[1];
    float* out = (float*)d_out;

    char* ws = (char*)d_ws;
    double* loss            = (double*)(ws + CTRL_OFF);
    unsigned int* pair_cnt  = (unsigned int*)(ws + CTRL_OFF + 8);
    unsigned int* done      = (unsigned int*)(ws + CTRL_OFF + 12);
    unsigned int* ctrl      = (unsigned int*)(ws + CTRL_OFF);
    float* magf             = (float*)(ws + MAGF_OFF);
    float* srow             = (float*)(ws + SROW_OFF);
    float* part             = (float*)(ws + PART_OFF);
    signed char* Xq         = (signed char*)(ws + XQ_OFF);
    uint2* pairs            = (uint2*)(ws + PAIR_OFF);
    unsigned int cap = 0;
    if (ws_size > PAIR_OFF + 8) cap = (unsigned int)((ws_size - PAIR_OFF) / 8);

    quant_kernel<<<NROWS / 4, 256, 0, stream>>>(X, Xq, magf, srow, ctrl);

    sim_mfma<<<NBLK, 256, 0, stream>>>(Xq, tgt, magf, srow, part, pair_cnt,
                                       pairs, cap);

    pair_kernel<<<256, 256, 0, stream>>>(pairs, pair_cnt, part, cap, loss,
                                         done, out);
}

// Round 22
// 48.562 us; speedup vs baseline: 1.0472x; 1.0472x over previous
//
#include <hip/hip_runtime.h>
#include <math.h>

#define NROWS 4096
#define DIM   512
#define BM    128
#define BKB   128               // K-tile in elements(=bytes, int8)
#define NKT   (DIM / BKB)       // 4
#define NTILE (NROWS / BM)      // 32
#define NBLK  (NTILE * (NTILE + 1) / 2)  // 528 (= 8 x 66)

typedef __attribute__((ext_vector_type(4))) float f32x4;
typedef __attribute__((ext_vector_type(4))) int   i32x4;
typedef __attribute__((ext_vector_type(8))) short bf16x8;

// ws layout (bytes):
// [0, 32)            ctrl: double loss | uint pair_cnt | uint done | pad
// [64,    16448)     float magf[4096]   (real-unit squared norms)
// [16448, 32832)     float srow[4096]   (per-row dequant scale)
// [32832, 49216)     float row_neg[4096]
// [49216, 311360)    ushort part_t[4096][32]  (bf16 negsum partials)
// [311360, 2408512)  int8 Xq[4096*512]  (2 MB)
// [2408512, ...)     pairs: uint2 {(i<<16)|j, float_bits(dist)}
#define CTRL_OFF 0
#define MAGF_OFF 64
#define SROW_OFF (MAGF_OFF + NROWS * 4)            // 16448
#define RN_OFF   (SROW_OFF + NROWS * 4)            // 32832
#define PART_OFF (RN_OFF + NROWS * 4)              // 49216
#define XQ_OFF   (PART_OFF + NROWS * NTILE * 2)    // 311360
#define PAIR_OFF (XQ_OFF + NROWS * DIM)            // 2408512

__device__ inline unsigned short f2bf(float f) {
    unsigned int u = __float_as_uint(f);
    unsigned int r = (u + 0x7fffu + ((u >> 16) & 1u)) >> 16;   // RTNE
    return (unsigned short)r;
}
__device__ inline float bf2f(unsigned short u) {
    return __uint_as_float((unsigned int)u << 16);
}

// quantize with PER-ROW scale (exact: d2 = |s_i q_i - s_j q_j|^2) + ctrl zero.
// One wave per row; row (2 KB) held in registers, single pass over X.
__global__ void quant_kernel(const float* __restrict__ X,
                             signed char* __restrict__ Xq,
                             float* __restrict__ magf,
                             float* __restrict__ srow,
                             unsigned int* __restrict__ ctrl) {
    if (blockIdx.x == 0 && threadIdx.x < 4) ctrl[threadIdx.x] = 0u;
    int row  = blockIdx.x * 4 + (threadIdx.x >> 6);
    int lane = threadIdx.x & 63;
    const float4* p = reinterpret_cast<const float4*>(X + (size_t)row * DIM);
    float4 v0 = p[lane], v1 = p[lane + 64];
    float m = fmaxf(fmaxf(fmaxf(fabsf(v0.x), fabsf(v0.y)),
                          fmaxf(fabsf(v0.z), fabsf(v0.w))),
                    fmaxf(fmaxf(fabsf(v1.x), fabsf(v1.y)),
                          fmaxf(fabsf(v1.z), fabsf(v1.w))));
#pragma unroll
    for (int o = 1; o < 64; o <<= 1) m = fmaxf(m, __shfl_xor(m, o));
    float s = m > 1e-20f ? 126.0f / m : 1.0f;

    int c[8];
    c[0] = (int)rintf(v0.x * s); c[1] = (int)rintf(v0.y * s);
    c[2] = (int)rintf(v0.z * s); c[3] = (int)rintf(v0.w * s);
    c[4] = (int)rintf(v1.x * s); c[5] = (int)rintf(v1.y * s);
    c[6] = (int)rintf(v1.z * s); c[7] = (int)rintf(v1.w * s);
    int acc = 0;
#pragma unroll
    for (int k = 0; k < 8; k++) {
        c[k] = max(-127, min(127, c[k]));
        acc += c[k] * c[k];
    }
    unsigned int* o = reinterpret_cast<unsigned int*>(Xq + (size_t)row * DIM);
    o[lane] = (unsigned int)(c[0] & 255) | ((unsigned int)(c[1] & 255) << 8) |
              ((unsigned int)(c[2] & 255) << 16) | ((unsigned int)(c[3] & 255) << 24);
    o[lane + 64] = (unsigned int)(c[4] & 255) | ((unsigned int)(c[5] & 255) << 8) |
                   ((unsigned int)(c[6] & 255) << 16) | ((unsigned int)(c[7] & 255) << 24);
#pragma unroll
    for (int off = 32; off; off >>= 1) acc += __shfl_down(acc, off);
    if (lane == 0) {
        float sr = 1.0f / s;                    // dequant scale
        srow[row] = sr;
        magf[row] = (sr * sr) * (float)acc;     // real-unit |x_q|^2
    }
}

// int8 MFMA GEMM, exact quantized distances. R17's proven structure:
// 128x128 triangular tiles, rolled NKT=4 K-loop, 8x16B-chunk XOR swizzle.
__global__ __launch_bounds__(256, 3) void sim_mfma(
        const signed char* __restrict__ Xq, const int* __restrict__ tgt,
        const float* __restrict__ magf, const float* __restrict__ srow,
        unsigned short* __restrict__ part,
        unsigned int* __restrict__ pair_cnt, uint2* __restrict__ pairs,
        unsigned int cap) {
    __shared__ signed char As[BM * BKB];   // 16 KB
    __shared__ signed char Bs[BM * BKB];   // 16 KB

    const int tid  = threadIdx.x;
    const int lane = tid & 63;
    const int wid  = tid >> 6;        // 4 waves: 2x2 of 64x64
    const int wr   = wid >> 1, wc = wid & 1;
    const int l15  = lane & 15;
    const int lg   = lane >> 4;       // 0..3

    // XCD swizzle: 528 = 8 x 66, contiguous runs per XCD
    int b = blockIdx.x;
    int t = (b & 7) * 66 + (b >> 3);
    int bi = (int)((65.0f - sqrtf(4225.0f - 8.0f * (float)t)) * 0.5f);
    if (bi < 0) bi = 0;
    if (bi > NTILE - 1) bi = NTILE - 1;
    while ((65 * (bi + 1) - (bi + 1) * (bi + 1)) / 2 <= t) bi++;
    while ((65 * bi - bi * bi) / 2 > t) bi--;
    int bj = bi + (t - (65 * bi - bi * bi) / 2);
    const int rowBase = bi * BM;
    const int colBase = bj * BM;
    const bool offd = (bi != bj);

    i32x4 acc[4][4];
#pragma unroll
    for (int m = 0; m < 4; m++)
#pragma unroll
        for (int n = 0; n < 4; n++) acc[m][n] = (i32x4){0, 0, 0, 0};

    // ROLLED K-loop. Row = 128 B = 8 x 16B chunks; LDS slot (r, ch) holds
    // global chunk ch^(r&7) (read-side XOR, linear LDS dest - rule #21).
#pragma unroll 1
    for (int kt = 0; kt < NKT; kt++) {
        const int k0 = kt * BKB;
        __syncthreads();
#pragma unroll
        for (int c = 0; c < 4; c++) {
            int chunkBase = (c * 4 + wid) * 64;      // wave-uniform
            int idx = chunkBase + lane;              // 0..1023
            int r   = idx >> 3;
            int ch  = idx & 7;
            int gch = ch ^ (r & 7);
            const signed char* ga = Xq + (size_t)(rowBase + r) * DIM + k0 + gch * 16;
            __builtin_amdgcn_global_load_lds(
                (const __attribute__((address_space(1))) void*)ga,
                (__attribute__((address_space(3))) void*)(As + chunkBase * 16),
                16, 0, 0);
            const signed char* gb = Xq + (size_t)(colBase + r) * DIM + k0 + gch * 16;
            __builtin_amdgcn_global_load_lds(
                (const __attribute__((address_space(1))) void*)gb,
                (__attribute__((address_space(3))) void*)(Bs + chunkBase * 16),
                16, 0, 0);
        }
        __syncthreads();

#pragma unroll
        for (int ksub = 0; ksub < 2; ksub++) {
            i32x4 af[4], bf[4];
#pragma unroll
            for (int m = 0; m < 4; m++) {
                int ra = wr * 64 + m * 16 + l15;
                int cs = (ksub * 4 + lg) ^ (ra & 7);
                af[m] = *reinterpret_cast<const i32x4*>(&As[ra * BKB + cs * 16]);
            }
#pragma unroll
            for (int n = 0; n < 4; n++) {
                int rb = wc * 64 + n * 16 + l15;
                int cs = (ksub * 4 + lg) ^ (rb & 7);
                bf[n] = *reinterpret_cast<const i32x4*>(&Bs[rb * BKB + cs * 16]);
            }
#pragma unroll
            for (int m = 0; m < 4; m++)
#pragma unroll
                for (int n = 0; n < 4; n++)
                    acc[m][n] = __builtin_amdgcn_mfma_i32_16x16x64_i8(
                        af[m], bf[n], acc[m][n], 0, 0, 0);
        }
    }

    // ---- fused epilogue ----
    // C/D layout: col = lane&15, row = (lane>>4)*4 + reg (dtype-independent)
    int gcol[4], tgj[4];
    float mj[4], sj[4];
#pragma unroll
    for (int n = 0; n < 4; n++) {
        gcol[n] = colBase + wc * 64 + n * 16 + l15;
        tgj[n]  = tgt[gcol[n]];
        mj[n]   = magf[gcol[n]];
        sj[n]   = srow[gcol[n]];
    }
    int grow[4][4], tgi[4][4];
    float mi[4][4], si[4][4];
#pragma unroll
    for (int m = 0; m < 4; m++)
#pragma unroll
        for (int q = 0; q < 4; q++) {
            grow[m][q] = rowBase + wr * 64 + m * 16 + lg * 4 + q;
            tgi[m][q]  = tgt[grow[m][q]];
            mi[m][q]   = magf[grow[m][q]];
            si[m][q]   = srow[grow[m][q]];
        }

    float negrow[4][4];
    float negcol[4] = {0.f, 0.f, 0.f, 0.f};
#pragma unroll
    for (int m = 0; m < 4; m++)
#pragma unroll
        for (int q = 0; q < 4; q++) negrow[m][q] = 0.f;

    // pass A: real-unit d2 -> dist (overwrites acc with dist bits)
    int mycnt = 0;
#pragma unroll
    for (int m = 0; m < 4; m++)
#pragma unroll
        for (int n = 0; n < 4; n++)
#pragma unroll
            for (int q = 0; q < 4; q++) {
                float ss   = si[m][q] * sj[n];
                float d2   = (mi[m][q] + mj[n]) - 2.0f * (ss * (float)acc[m][n][q]);
                float dist = d2 > 0.f ? sqrtf(d2) : 0.f;
                acc[m][n][q] = __float_as_int(dist);
                if (tgi[m][q] != tgj[n]) {
                    if (dist != 0.f) {
                        float e = __expf(1.0f - dist);
                        negrow[m][q] += e;
                        if (offd) negcol[n] += e;
                    }
                } else if (grow[m][q] < gcol[n]) {
                    mycnt++;
                }
            }

    __syncthreads();   // K-loop LDS dead; overlay epilogue buffers
    float* rowbuf = (float*)&As[0];            // [2][128] floats
    float* colbuf = (float*)&As[2048];         // [2][128] floats
    unsigned int* scan = (unsigned int*)&Bs[0];

#pragma unroll
    for (int m = 0; m < 4; m++)
#pragma unroll
        for (int q = 0; q < 4; q++) {
            float v = negrow[m][q];
            v += __shfl_xor(v, 1); v += __shfl_xor(v, 2);
            v += __shfl_xor(v, 4); v += __shfl_xor(v, 8);
            if (l15 == 0) rowbuf[wc * 128 + wr * 64 + m * 16 + lg * 4 + q] = v;
        }
#pragma unroll
    for (int n = 0; n < 4; n++) {
        float v = negcol[n];
        v += __shfl_xor(v, 16); v += __shfl_xor(v, 32);
        if (lg == 0) colbuf[wr * 128 + wc * 64 + n * 16 + l15] = v;
    }

    unsigned int pc = (unsigned int)mycnt;
    unsigned int incl = pc;
#pragma unroll
    for (int d = 1; d < 64; d <<= 1) {
        unsigned int tshf = __shfl_up(incl, d);
        if (lane >= d) incl += tshf;
    }
    if (lane == 63) scan[wid] = incl;
    __syncthreads();

    if (tid < BM) {
        float rv = rowbuf[tid] + rowbuf[128 + tid];
        part[(size_t)(rowBase + tid) * NTILE + bj] = f2bf(rv);
        if (offd) {
            float cv = colbuf[tid] + colbuf[128 + tid];
            part[(size_t)(colBase + tid) * NTILE + bi] = f2bf(cv);
        }
    }

    unsigned int woff = 0;
#pragma unroll
    for (int w = 0; w < 4; w++)
        if (w < wid) woff += scan[w];
    unsigned int btot = scan[0] + scan[1] + scan[2] + scan[3];
    if (tid == 0) scan[4] = btot ? atomicAdd(pair_cnt, btot) : 0u;
    __syncthreads();
    unsigned int mybase = scan[4] + woff + (incl - pc);

    if (pc) {
        unsigned int idx = mybase;
#pragma unroll
        for (int m = 0; m < 4; m++)
#pragma unroll
            for (int n = 0; n < 4; n++)
#pragma unroll
                for (int q = 0; q < 4; q++) {
                    if (tgi[m][q] == tgj[n] && grow[m][q] < gcol[n]) {
                        if (idx < cap) {
                            uint2 e;
                            e.x = ((unsigned int)grow[m][q] << 16) | (unsigned int)gcol[n];
                            e.y = (unsigned int)acc[m][n][q];   // dist bits
                            pairs[idx] = e;
                        }
                        idx++;
                    }
                }
    }
}

// row_neg[r] = sum of 32 bf16 partials (contiguous 64B stripe per row)
__global__ void reduce_kernel(const unsigned short* __restrict__ part,
                              float* __restrict__ row_neg) {
    int r = blockIdx.x * 256 + threadIdx.x;
    const bf16x8* p = reinterpret_cast<const bf16x8*>(part + (size_t)r * NTILE);
    float s = 0.f;
#pragma unroll
    for (int k = 0; k < 4; k++) {
        bf16x8 a = p[k];
#pragma unroll
        for (int u = 0; u < 8; u++) s += bf2f((unsigned short)a[u]);
    }
    row_neg[r] = s;
}

// pair loss sum + fused finalize
__global__ void pair_kernel(const uint2* __restrict__ pairs,
                            const unsigned int* __restrict__ pair_cnt,
                            const float* __restrict__ row_neg,
                            unsigned int cap, double* __restrict__ loss,
                            unsigned int* __restrict__ done,
                            float* __restrict__ out) {
    __shared__ double red[256];
    unsigned int n = *pair_cnt;
    if (n > cap) n = cap;
    double local = 0.0;
    for (unsigned int p = blockIdx.x * blockDim.x + threadIdx.x; p < n;
         p += gridDim.x * blockDim.x) {
        uint2 e = pairs[p];
        int i = (int)(e.x >> 16), j = (int)(e.x & 0xffffu);
        float d = __int_as_float((int)e.y);
        float J = logf(row_neg[i] + row_neg[j]) + d;
        if (J > 0.f) local += (double)J * (double)J;
    }
    red[threadIdx.x] = local;
    __syncthreads();
    for (int s = 128; s; s >>= 1) {
        if (threadIdx.x < (unsigned)s) red[threadIdx.x] += red[threadIdx.x + s];
        __syncthreads();
    }
    if (threadIdx.x == 0) {
        atomicAdd(loss, red[0]);
        __threadfence();
        unsigned int tk = atomicAdd(done, 1u);
        if (tk == gridDim.x - 1) {
            double l = atomicAdd(loss, 0.0);
            out[0] = (float)(l / (2.0 * (double)(*pair_cnt)));
        }
    }
}

extern "C" void kernel_launch(void* const* d_in, const int* in_sizes, int n_in,
                              void* d_out, int out_size, void* d_ws, size_t ws_size,
                              hipStream_t stream) {
    const float* X = (const float*)d_in[0];
    const int* tgt = (const int*)d_in[1];
    float* out = (float*)d_out;

    char* ws = (char*)d_ws;
    double* loss            = (double*)(ws + CTRL_OFF);
    unsigned int* pair_cnt  = (unsigned int*)(ws + CTRL_OFF + 8);
    unsigned int* done      = (unsigned int*)(ws + CTRL_OFF + 12);
    unsigned int* ctrl      = (unsigned int*)(ws + CTRL_OFF);
    float* magf             = (float*)(ws + MAGF_OFF);
    float* srow             = (float*)(ws + SROW_OFF);
    float* row_neg          = (float*)(ws + RN_OFF);
    unsigned short* part    = (unsigned short*)(ws + PART_OFF);
    signed char* Xq         = (signed char*)(ws + XQ_OFF);
    uint2* pairs            = (uint2*)(ws + PAIR_OFF);
    unsigned int cap = 0;
    if (ws_size > PAIR_OFF + 8) cap = (unsigned int)((ws_size - PAIR_OFF) / 8);

    quant_kernel<<<NROWS / 4, 256, 0, stream>>>(X, Xq, magf, srow, ctrl);

    sim_mfma<<<NBLK, 256, 0, stream>>>(Xq, tgt, magf, srow, part, pair_cnt,
                                       pairs, cap);

    reduce_kernel<<<NROWS / 256, 256, 0, stream>>>(part, row_neg);

    pair_kernel<<<256, 256, 0, stream>>>(pairs, pair_cnt, row_neg, cap, loss,
                                         done, out);
}